// Round 13
// baseline (262.126 us; speedup 1.0000x reference)
//
#include <hip/hip_runtime.h>
#include <math.h>

#define NE 256
#define EDIM 1024
#define HW 1024
#define NPIX 16384
#define OUT_ELEMS 16777216

typedef short short8 __attribute__((ext_vector_type(8)));
typedef float f32x4 __attribute__((ext_vector_type(4)));
typedef float f32x16 __attribute__((ext_vector_type(16)));

// ---------------- fast-path workspace layout (bytes) ----------------
#define WS_HIST   0          // int[256]
#define WS_LOSS   1024       // float
#define WS_ZSQ    1028       // float
#define WS_FBITS  2048       // uint[512] bitmap of tie-flagged pixels (2 KB)
#define WS_T      4096       // float[1024*256] = 1 MB
#define WS_MEMSET 1052672
// [no-init region]
#define WS_CE2    1052672    // float[256]
#define WS_IDX    1053696    // int[16384]
#define WS_EH     1119232    // ushort[256*1024] = 512 KB (bf16 high)
#define WS_EL     1643520    // ushort[256*1024] = 512 KB (bf16 residual)
#define WS_NEED   2167808

#define DELTA 0.02f          // tie-guard; bf16x3 score sigma ~2.5e-4 -> ~80 sigma

// ---------------- fallback (round-1) workspace layout ----------------
#define WO_CE2  0
#define WO_HIST 1024
#define WO_LOSS 2048
#define WO_IDX  4096
#define WO_T    69632
#define WO_TOTAL 1118208

__device__ __forceinline__ unsigned short f2bf(float f) {
    unsigned u = __float_as_uint(f);
    unsigned r = u + 0x7FFFu + ((u >> 16) & 1u);   // RNE
    return (unsigned short)(r >> 16);
}
__device__ __forceinline__ float bf2f(unsigned short h) {
    return __uint_as_float(((unsigned)h) << 16);
}

// async global->LDS, 16 B per lane; lptr must be wave-uniform (HW adds lane*16)
__device__ __forceinline__ void stage16(const void* g, void* l) {
    __builtin_amdgcn_global_load_lds(
        (const __attribute__((address_space(1))) unsigned int*)g,
        (__attribute__((address_space(3))) unsigned int*)l, 16, 0, 0);
}

// ------- fused prep: emb -> eh/el bf16 split AND ce2 = 0.5||e||^2 ----------
__global__ __launch_bounds__(64) void k_prep(const float* __restrict__ emb,
                                             unsigned short* __restrict__ eh,
                                             unsigned short* __restrict__ el,
                                             float* __restrict__ ce2) {
    int j = blockIdx.x;
    int l = threadIdx.x;
    const float* row = emb + ((size_t)j << 10);
    float s = 0.f;
    #pragma unroll
    for (int i = 0; i < 4; i++) {
        float4 v = *(const float4*)(row + l * 4 + 256 * i);
        s += v.x * v.x + v.y * v.y + v.z * v.z + v.w * v.w;
        unsigned short h0 = f2bf(v.x), h1 = f2bf(v.y), h2 = f2bf(v.z), h3 = f2bf(v.w);
        uint2 hp, lp;
        hp.x = (unsigned)h0 | ((unsigned)h1 << 16);
        hp.y = (unsigned)h2 | ((unsigned)h3 << 16);
        lp.x = (unsigned)f2bf(v.x - bf2f(h0)) | ((unsigned)f2bf(v.y - bf2f(h1)) << 16);
        lp.y = (unsigned)f2bf(v.z - bf2f(h2)) | ((unsigned)f2bf(v.w - bf2f(h3)) << 16);
        *(uint2*)(eh + ((size_t)j << 10) + l * 4 + 256 * i) = hp;
        *(uint2*)(el + ((size_t)j << 10) + l * 4 + 256 * i) = lp;
    }
    #pragma unroll
    for (int m = 32; m; m >>= 1) s += __shfl_down(s, m, 64);
    if (l == 0) ce2[j] = 0.5f * s;
}

// ---------------- T[o][j] = sum_c w[o][c]*emb[j][c] (split-K, atomics) ----
__global__ __launch_bounds__(256) void k_wT(const float* __restrict__ w,
                                            const float* __restrict__ emb,
                                            float* __restrict__ T) {
    __shared__ float wt[64 * 17];
    __shared__ float et[64 * 17];
    int t = threadIdx.x;
    int j0 = blockIdx.x * 64;
    int o0 = blockIdx.y * 64;
    int kb = blockIdx.z * 256;
    int to = t & 15, tj = t >> 4;
    float acc[4][4] = {};
    int lr = t >> 2, lk = (t & 3) * 4;
    for (int kk = kb; kk < kb + 256; kk += 16) {
        float4 wv = *(const float4*)(w + (size_t)(o0 + lr) * EDIM + kk + lk);
        float4 ev = *(const float4*)(emb + (size_t)(j0 + lr) * EDIM + kk + lk);
        __syncthreads();
        wt[lr * 17 + lk + 0] = wv.x; wt[lr * 17 + lk + 1] = wv.y;
        wt[lr * 17 + lk + 2] = wv.z; wt[lr * 17 + lk + 3] = wv.w;
        et[lr * 17 + lk + 0] = ev.x; et[lr * 17 + lk + 1] = ev.y;
        et[lr * 17 + lk + 2] = ev.z; et[lr * 17 + lk + 3] = ev.w;
        __syncthreads();
        #pragma unroll
        for (int k = 0; k < 16; k++) {
            float a[4], b[4];
            #pragma unroll
            for (int i = 0; i < 4; i++) a[i] = wt[(to * 4 + i) * 17 + k];
            #pragma unroll
            for (int i = 0; i < 4; i++) b[i] = et[(tj * 4 + i) * 17 + k];
            #pragma unroll
            for (int i = 0; i < 4; i++)
                #pragma unroll
                for (int jx = 0; jx < 4; jx++) acc[i][jx] += a[i] * b[jx];
        }
    }
    #pragma unroll
    for (int i = 0; i < 4; i++)
        #pragma unroll
        for (int jx = 0; jx < 4; jx++)
            atomicAdd(&T[(size_t)(o0 + to * 4 + i) * NE + j0 + tj * 4 + jx],
                      acc[i][jx]);
}

// ---------------- fused bf16x3 distance GEMM + argmin + tie-flagging -------
// v6: v5's HW-verified 32x32x16 math at 2 blocks/CU. 512 blocks x 256 thr;
// block = 32 px; 4 waves code-split (wave w: codes [w*64,+64), 2 code-tiles,
// acc = 2x f32x16). All waves share identical A fragments (z slice; waves
// 1-3 L1-hit). LDS = 2 chunk-buffers x 32 KB = 64 KB -> 2 blocks/CU =
// 8 waves/CU: stalls overlap across waves + independent barrier domains.
// Depth-1 counted pipeline: issue stage(c+1)+z(c+1) mid-body; at body top
// WAITV(16) drains exactly stage(c) (24 outstanding -> 16), lgkmcnt(0)
// retires own ds_reads before other waves' stage writes can land, then raw
// s_barrier. z-reg dependencies remain compiler-tracked (its waits are
// inserted independently of ours). 4-way argmin merge via 1.5 KB LDS.
__global__ __launch_bounds__(256) void k_dist(
        const float* __restrict__ z, const unsigned short* __restrict__ eh,
        const unsigned short* __restrict__ el,
        const float* __restrict__ ce2,
        int* __restrict__ idx_i, float* __restrict__ idx_f,
        int* __restrict__ hist, float* __restrict__ loss_s,
        float* __restrict__ zsq_acc, unsigned int* __restrict__ fbits) {
    __shared__ unsigned short sB[2][2][256 * 32];   // 2 bufs x (eh,el) x 16 KB = 64 KB
    __shared__ float v1h[4][32], v2h[4][32];
    __shared__ int   i1h[4][32];
    int t = threadIdx.x;
    int lane = t & 63, w = t >> 6;
    int cid = lane & 31, lh = lane >> 5;
    int c_base = w << 6;                 // wave's codes: [w*64, +64)
    int cswz = (cid >> 1) & 3;           // read-side slot swizzle
    int px0 = blockIdx.x * 32;           // 32-px blocks never cross an image
    int b = px0 >> 10;
    const float* zp = z + (((size_t)b) << 20) + (px0 & 1023) + cid;
    int sc = t >> 2, qp = t & 3;         // staging: code row, physical slot
    int ql = qp ^ ((sc >> 1) & 3);       // pre-swizzled source slot

    f32x16 acc[2];
    #pragma unroll
    for (int nt = 0; nt < 2; nt++)
        #pragma unroll
        for (int i = 0; i < 16; i++) acc[nt][i] = 0.f;

    float zvA[16], zvB[16];
    float zsq = 0.f;

// stage chunk c (k-dims [c*32, +32)) into LDS buffer B: 8 wave-instrs
#define STAGE(c, B) do {                                                        \
    int kk_ = (c) * 32;                                                         \
    _Pragma("unroll")                                                           \
    for (int i_ = 0; i_ < 4; i_++) {                                            \
        stage16(eh + (((size_t)(i_ * 64 + sc)) << 10) + kk_ + ql * 8,           \
                &sB[B][0][(i_ * 256 + w * 64) * 8]);                            \
        stage16(el + (((size_t)(i_ * 64 + sc)) << 10) + kk_ + ql * 8,           \
                &sB[B][1][(i_ * 256 + w * 64) * 8]);                            \
    } } while (0)

// load this lane's 32-px z slice for chunk c: 16 dword loads
#define ZLOAD(c, ZV) do {                                                       \
    int kk_ = (c) * 32;                                                         \
    _Pragma("unroll")                                                           \
    for (int j_ = 0; j_ < 8; j_++) {                                            \
        ZV[j_]     = zp[((size_t)(kk_ + lh * 8 + j_)) << 10];                   \
        ZV[8 + j_] = zp[((size_t)(kk_ + 16 + lh * 8 + j_)) << 10];              \
    } } while (0)

// counted wait + scheduler fence (rule #18)
#define WAITV(n) do {                                                           \
    asm volatile("s_waitcnt vmcnt(" #n ")" ::: "memory");                       \
    __builtin_amdgcn_sched_barrier(0); } while (0)

// issue-order fence (no wait): pins vmem issue order so vmcnt counts are exact
#define FENCE() do {                                                            \
    asm volatile("" ::: "memory");                                              \
    __builtin_amdgcn_sched_barrier(0); } while (0)

// one chunk: WAITV(16) drains stage(c); own-ds_read drain; barrier; split
// z(c); issue stage(c+1)+z(c+1); 12 MFMAs over buf B
#define BODY(c, B, ZV, PRE, B2, ZV2) do {                                       \
    WAITV(16);                                                                  \
    asm volatile("s_waitcnt lgkmcnt(0)" ::: "memory");                          \
    __builtin_amdgcn_sched_barrier(0);                                          \
    __builtin_amdgcn_s_barrier();                                               \
    FENCE();                                                                    \
    short8 ah0, al0, ah1, al1;                                                  \
    _Pragma("unroll")                                                           \
    for (int j_ = 0; j_ < 8; j_++) {                                            \
        float z0_ = ZV[j_], z1_ = ZV[8 + j_];                                   \
        zsq += z0_ * z0_ + z1_ * z1_;                                           \
        unsigned short h0_ = f2bf(z0_), h1_ = f2bf(z1_);                        \
        ((unsigned short*)&ah0)[j_] = h0_;                                      \
        ((unsigned short*)&al0)[j_] = f2bf(z0_ - bf2f(h0_));                    \
        ((unsigned short*)&ah1)[j_] = h1_;                                      \
        ((unsigned short*)&al1)[j_] = f2bf(z1_ - bf2f(h1_));                    \
    }                                                                           \
    if (PRE) { STAGE((c) + 1, B2); FENCE(); ZLOAD((c) + 1, ZV2); }              \
    _Pragma("unroll")                                                           \
    for (int t_ = 0; t_ < 2; t_++) {                                            \
        int crow_ = (c_base + t_ * 32 + cid) * 32;                              \
        int sp0_ = lh ^ cswz;                                                   \
        int sp1_ = (2 + lh) ^ cswz;                                             \
        short8 bh0_ = *(const short8*)&sB[B][0][crow_ + sp0_ * 8];              \
        short8 bl0_ = *(const short8*)&sB[B][1][crow_ + sp0_ * 8];              \
        short8 bh1_ = *(const short8*)&sB[B][0][crow_ + sp1_ * 8];              \
        short8 bl1_ = *(const short8*)&sB[B][1][crow_ + sp1_ * 8];              \
        acc[t_] = __builtin_amdgcn_mfma_f32_32x32x16_bf16(ah0, bh0_, acc[t_], 0, 0, 0); \
        acc[t_] = __builtin_amdgcn_mfma_f32_32x32x16_bf16(ah0, bl0_, acc[t_], 0, 0, 0); \
        acc[t_] = __builtin_amdgcn_mfma_f32_32x32x16_bf16(al0, bh0_, acc[t_], 0, 0, 0); \
        acc[t_] = __builtin_amdgcn_mfma_f32_32x32x16_bf16(ah1, bh1_, acc[t_], 0, 0, 0); \
        acc[t_] = __builtin_amdgcn_mfma_f32_32x32x16_bf16(ah1, bl1_, acc[t_], 0, 0, 0); \
        acc[t_] = __builtin_amdgcn_mfma_f32_32x32x16_bf16(al1, bh1_, acc[t_], 0, 0, 0); \
    } } while (0)

    // prologue: chunk 0 in flight (24 outstanding, order pinned)
    STAGE(0, 0); FENCE(); ZLOAD(0, zvA);

    // main loop: 32 chunks, 2 buffers; body c stages c+1 into the other buf
    for (int mi = 0; mi < 16; mi++) {
        BODY(2 * mi,     0, zvA, (mi < 15 || 1) && (2 * mi     < 31), 1, zvB);
        BODY(2 * mi + 1, 1, zvB, (2 * mi + 1 < 31),                   0, zvA);
    }

#undef STAGE
#undef ZLOAD
#undef WAITV
#undef FENCE
#undef BODY

    // zsq: all waves computed identical z; only wave 0 contributes
    #pragma unroll
    for (int msk = 32; msk; msk >>= 1) zsq += __shfl_down(zsq, msk, 64);
    if (w == 0 && lane == 0) atomicAdd(zsq_acc, zsq);

    // ----- per-wave argmin over its 64 codes for 32 px -----
    float c2v[2];
    #pragma unroll
    for (int t_ = 0; t_ < 2; t_++) c2v[t_] = ce2[c_base + t_ * 32 + cid];

    #pragma unroll
    for (int r = 0; r < 16; r++) {       // px row = (r&3)+8*(r>>2)+4*lh
        float s0 = c2v[0] - acc[0][r];   // code = c_base + cid
        float s1 = c2v[1] - acc[1][r];   // code = c_base + 32 + cid
        float v1, v2; int i1;
        if (s0 <= s1) { v1 = s0; i1 = c_base + cid;      v2 = s1; }
        else          { v1 = s1; i1 = c_base + 32 + cid; v2 = s0; }
        #pragma unroll
        for (int msk = 1; msk < 32; msk <<= 1) {
            float ov1 = __shfl_xor(v1, msk, 64);
            int   oi1 = __shfl_xor(i1, msk, 64);
            float ov2 = __shfl_xor(v2, msk, 64);
            float nv2 = fminf(fminf(v2, ov2), fmaxf(v1, ov1));
            if (ov1 < v1 || (ov1 == v1 && oi1 < i1)) { v1 = ov1; i1 = oi1; }
            v2 = nv2;
        }
        if (cid == 0) {
            int pl = (r & 3) + 8 * (r >> 2) + 4 * lh;
            v1h[w][pl] = v1; v2h[w][pl] = v2; i1h[w][pl] = i1;
        }
    }
    __syncthreads();
    // ----- wave 0: merge the 4 code-groups (ascending group = ascending
    // code ranges, so strict < keeps the lowest winning code on ties) -----
    if (w == 0) {
        float lsum = 0.f;
        if (lane < 32) {
            int p = lane;
            float v1 = v1h[0][p], v2 = v2h[0][p];
            int   i1 = i1h[0][p];
            #pragma unroll
            for (int g = 1; g < 4; g++) {
                float ov1 = v1h[g][p], ov2 = v2h[g][p];
                int   oi1 = i1h[g][p];
                float nv2 = fminf(fminf(v2, ov2), fmaxf(v1, ov1));
                if (ov1 < v1) { v1 = ov1; i1 = oi1; }
                v2 = nv2;
            }
            int px = px0 + p;
            idx_i[px] = i1;
            idx_f[px] = (float)i1;
            atomicAdd(&hist[i1], 1);
            if (v2 - v1 < DELTA)
                atomicOr(&fbits[px >> 5], 1u << (px & 31));
            lsum = v1;
        }
        #pragma unroll
        for (int msk = 1; msk < 32; msk <<= 1) lsum += __shfl_xor(lsum, msk, 64);
        if (lane == 0) atomicAdd(loss_s, lsum);
    }
}

// ---------------- exact fp32 re-argmin for tie-flagged pixels --------------
__global__ __launch_bounds__(256) void k_cleanup(const float* __restrict__ z,
        const float* __restrict__ emb, const float* __restrict__ ce2,
        const unsigned int* __restrict__ fbits,
        int* __restrict__ idx_i, float* __restrict__ idx_f, int* __restrict__ hist) {
    __shared__ float zs[1024];
    __shared__ float rv[4];
    __shared__ int ri[4];
    int t = threadIdx.x;
    const float* er = emb + (size_t)t * EDIM;
    for (int px = blockIdx.x; px < NPIX; px += gridDim.x) {
        if (!(fbits[px >> 5] & (1u << (px & 31)))) continue;   // uniform per block
        int b = px >> 10, p = px & 1023;
        const float* zb = z + (((size_t)b) << 20) + p;
        #pragma unroll
        for (int r = 0; r < 4; r++) {
            int c = t + 256 * r;
            zs[c] = zb[((size_t)c) << 10];
        }
        __syncthreads();
        float d0 = 0.f, d1 = 0.f, d2 = 0.f, d3 = 0.f;
        #pragma unroll 4
        for (int c = 0; c < EDIM; c += 16) {
            float4 e0 = *(const float4*)(er + c);
            float4 e1 = *(const float4*)(er + c + 4);
            float4 e2 = *(const float4*)(er + c + 8);
            float4 e3 = *(const float4*)(er + c + 12);
            d0 += e0.x * zs[c]      + e0.y * zs[c + 1]  + e0.z * zs[c + 2]  + e0.w * zs[c + 3];
            d1 += e1.x * zs[c + 4]  + e1.y * zs[c + 5]  + e1.z * zs[c + 6]  + e1.w * zs[c + 7];
            d2 += e2.x * zs[c + 8]  + e2.y * zs[c + 9]  + e2.z * zs[c + 10] + e2.w * zs[c + 11];
            d3 += e3.x * zs[c + 12] + e3.y * zs[c + 13] + e3.z * zs[c + 14] + e3.w * zs[c + 15];
        }
        float sv = ce2[t] - ((d0 + d1) + (d2 + d3));
        int bi = t;
        #pragma unroll
        for (int msk = 1; msk < 64; msk <<= 1) {
            float ov = __shfl_xor(sv, msk, 64);
            int oi = __shfl_xor(bi, msk, 64);
            if (ov < sv || (ov == sv && oi < bi)) { sv = ov; bi = oi; }
        }
        if ((t & 63) == 0) { rv[t >> 6] = sv; ri[t >> 6] = bi; }
        __syncthreads();
        if (t == 0) {
            float v = rv[0]; int ix = ri[0];
            for (int ww = 1; ww < 4; ww++)
                if (rv[ww] < v || (rv[ww] == v && ri[ww] < ix)) { v = rv[ww]; ix = ri[ww]; }
            int old = idx_i[px];
            if (ix != old) {
                idx_i[px] = ix; idx_f[px] = (float)ix;
                atomicAdd(&hist[ix], 1); atomicSub(&hist[old], 1);
            }
        }
        __syncthreads();
    }
}

// ---------------- round-1 fp32 argmin (fallback only) ----------------------
__global__ __launch_bounds__(64) void k_norms(const float* __restrict__ emb,
                                              float* __restrict__ ce2) {
    int j = blockIdx.x;
    int lane = threadIdx.x;
    const float* row = emb + (size_t)j * EDIM;
    float s = 0.f;
    #pragma unroll
    for (int i = 0; i < EDIM / 64; i++) {
        float v = row[lane + 64 * i];
        s += v * v;
    }
    #pragma unroll
    for (int m = 32; m; m >>= 1) s += __shfl_down(s, m, 64);
    if (lane == 0) ce2[j] = 0.5f * s;
}

__global__ __launch_bounds__(256) void k_argmin(const float* __restrict__ z,
                                                const float* __restrict__ emb,
                                                const float* __restrict__ ce2,
                                                int* __restrict__ idx_i,
                                                float* __restrict__ idx_f,
                                                int* __restrict__ hist,
                                                float* __restrict__ loss_acc) {
    __shared__ float zt[32 * 64];
    __shared__ float et[256 * 34];
    __shared__ float znorm_s[64];
    int t = threadIdx.x;
    int n0 = blockIdx.x * 64;
    int b = n0 >> 10;
    int p0 = n0 & 1023;
    const float* zb = z + (size_t)b * EDIM * HW;
    int tc = t & 31, tp = t >> 5;
    float acc[8][8] = {};
    float znorm = 0.f;
    for (int kk = 0; kk < EDIM; kk += 32) {
        #pragma unroll
        for (int i = 0; i < 16; i++) {
            int q = t + 256 * i;
            int code = q >> 4, k2 = q & 15;
            float2 v = *(const float2*)(emb + (size_t)code * EDIM + kk + k2 * 2);
            *(float2*)(et + code * 34 + k2 * 2) = v;
        }
        #pragma unroll
        for (int i = 0; i < 4; i++) {
            int q = t + 256 * i;
            int k = q >> 5, p2 = q & 31;
            float2 v = *(const float2*)(zb + (size_t)(kk + k) * HW + p0 + p2 * 2);
            *(float2*)(zt + k * 64 + p2 * 2) = v;
        }
        __syncthreads();
        if (t < 64) {
            #pragma unroll
            for (int k = 0; k < 32; k++) { float zz = zt[k * 64 + t]; znorm += zz * zz; }
        }
        #pragma unroll 4
        for (int k2 = 0; k2 < 16; k2++) {
            float2 ev[8], za[4], zb2[4];
            #pragma unroll
            for (int u = 0; u < 8; u++)
                ev[u] = *(float2*)(et + (tc + 32 * u) * 34 + k2 * 2);
            #pragma unroll
            for (int j = 0; j < 4; j++)
                za[j] = *(float2*)(zt + (2 * k2) * 64 + tp * 8 + 2 * j);
            #pragma unroll
            for (int j = 0; j < 4; j++)
                zb2[j] = *(float2*)(zt + (2 * k2 + 1) * 64 + tp * 8 + 2 * j);
            #pragma unroll
            for (int p = 0; p < 8; p++) {
                float z0 = (p & 1) ? za[p >> 1].y : za[p >> 1].x;
                float z1 = (p & 1) ? zb2[p >> 1].y : zb2[p >> 1].x;
                #pragma unroll
                for (int u = 0; u < 8; u++)
                    acc[p][u] += z0 * ev[u].x + z1 * ev[u].y;
            }
        }
        __syncthreads();
    }
    if (t < 64) znorm_s[t] = znorm;
    float minv[8];
    int mini[8];
    #pragma unroll
    for (int p = 0; p < 8; p++) { minv[p] = 3.4e38f; mini[p] = 0; }
    #pragma unroll
    for (int u = 0; u < 8; u++) {
        int code = tc + 32 * u;
        float cc2 = ce2[code];
        #pragma unroll
        for (int p = 0; p < 8; p++) {
            float s = cc2 - acc[p][u];
            if (s < minv[p] || (s == minv[p] && code < mini[p])) { minv[p] = s; mini[p] = code; }
        }
    }
    #pragma unroll
    for (int m = 1; m < 32; m <<= 1) {
        #pragma unroll
        for (int p = 0; p < 8; p++) {
            float ov = __shfl_xor(minv[p], m, 64);
            int oi = __shfl_xor(mini[p], m, 64);
            if (ov < minv[p] || (ov == minv[p] && oi < mini[p])) { minv[p] = ov; mini[p] = oi; }
        }
    }
    __syncthreads();
    if (tc == 0) {
        float dsum = 0.f;
        #pragma unroll
        for (int p = 0; p < 8; p++) {
            int lp = tp * 8 + p;
            int n = n0 + lp;
            idx_i[n] = mini[p];
            idx_f[n] = (float)mini[p];
            dsum += znorm_s[lp] + 2.f * minv[p];
            atomicAdd(&hist[mini[p]], 1);
        }
        atomicAdd(loss_acc, dsum);
    }
}

// ---------------- out[b][o][p] = T[o][idx[b][p]] + bias[o] -----------------
__global__ __launch_bounds__(256) void k_scatter(const float* __restrict__ T,
                                                 const float* __restrict__ bias,
                                                 const int* __restrict__ idx,
                                                 float* __restrict__ out) {
    __shared__ float Ts[16 * 256];
    __shared__ float bs[16];
    int t = threadIdx.x;
    int o0 = blockIdx.x * 16;
    int b = blockIdx.y;
    #pragma unroll
    for (int r = 0; r < 16; r++)
        Ts[r * 256 + t] = T[(size_t)(o0 + r) * NE + t];
    if (t < 16) bs[t] = bias[o0 + t];
    __syncthreads();
    int4 i4 = *(const int4*)(idx + b * HW + t * 4);
    #pragma unroll
    for (int r = 0; r < 16; r++) {
        const float* Tr = Ts + r * 256;
        float bb = bs[r];
        float4 v;
        v.x = Tr[i4.x] + bb;
        v.y = Tr[i4.y] + bb;
        v.z = Tr[i4.z] + bb;
        v.w = Tr[i4.w] + bb;
        *(float4*)(out + ((size_t)(b * EDIM + o0 + r) * HW) + t * 4) = v;
    }
}

// ---------------- finalize -------------------------------------------------
__global__ __launch_bounds__(256) void k_final_new(const int* __restrict__ hist,
                                                   const float* __restrict__ loss_s,
                                                   const float* __restrict__ zsq,
                                                   float* __restrict__ out) {
    __shared__ float red[4];
    int t = threadIdx.x;
    float em = (float)hist[t] * (1.0f / 16384.0f);
    float v = em * logf(em + 1e-10f);
    #pragma unroll
    for (int m = 32; m; m >>= 1) v += __shfl_down(v, m, 64);
    if ((t & 63) == 0) red[t >> 6] = v;
    __syncthreads();
    if (t == 0) {
        float s = red[0] + red[1] + red[2] + red[3];
        out[OUT_ELEMS] = (zsq[0] + 2.f * loss_s[0]) * 1.25f / 16777216.f;
        out[OUT_ELEMS + 1] = expf(-s);
    }
}

__global__ __launch_bounds__(256) void k_final_old(const int* __restrict__ hist,
                                                   const float* __restrict__ loss_acc,
                                                   float* __restrict__ out) {
    __shared__ float red[4];
    int t = threadIdx.x;
    float em = (float)hist[t] * (1.0f / 16384.0f);
    float v = em * logf(em + 1e-10f);
    #pragma unroll
    for (int m = 32; m; m >>= 1) v += __shfl_down(v, m, 64);
    if ((t & 63) == 0) red[t >> 6] = v;
    __syncthreads();
    if (t == 0) {
        float s = red[0] + red[1] + red[2] + red[3];
        out[OUT_ELEMS] = loss_acc[0] * 1.25f / 16777216.f;
        out[OUT_ELEMS + 1] = expf(-s);
    }
}

extern "C" void kernel_launch(void* const* d_in, const int* in_sizes, int n_in,
                              void* d_out, int out_size, void* d_ws, size_t ws_size,
                              hipStream_t stream) {
    (void)in_sizes; (void)n_in; (void)out_size;
    const float* z      = (const float*)d_in[0];
    const float* emb    = (const float*)d_in[1];
    const float* conv_w = (const float*)d_in[2];
    const float* conv_b = (const float*)d_in[3];
    float* out = (float*)d_out;

    if (ws_size >= WS_NEED) {
        // ---- fast path: 32x32 MFMA bf16x3 GEMM, 2 blocks/CU pipeline ----
        int*   hist     = (int*)((char*)d_ws + WS_HIST);
        float* loss_s   = (float*)((char*)d_ws + WS_LOSS);
        float* zsq      = (float*)((char*)d_ws + WS_ZSQ);
        unsigned int* fbits = (unsigned int*)((char*)d_ws + WS_FBITS);
        float* T        = (float*)((char*)d_ws + WS_T);
        float* ce2      = (float*)((char*)d_ws + WS_CE2);
        int*   idx_i    = (int*)((char*)d_ws + WS_IDX);
        unsigned short* eh = (unsigned short*)((char*)d_ws + WS_EH);
        unsigned short* el = (unsigned short*)((char*)d_ws + WS_EL);
        float* idx_f = out + OUT_ELEMS + 2;

        hipMemsetAsync(d_ws, 0, WS_MEMSET, stream);
        k_prep<<<NE, 64, 0, stream>>>(emb, eh, el, ce2);
        k_wT<<<dim3(4, 16, 4), 256, 0, stream>>>(conv_w, emb, T);
        k_dist<<<512, 256, 0, stream>>>(z, eh, el, ce2, idx_i, idx_f,
                                        hist, loss_s, zsq, fbits);
        k_cleanup<<<256, 256, 0, stream>>>(z, emb, ce2, fbits, idx_i, idx_f, hist);
        k_scatter<<<dim3(64, 16), 256, 0, stream>>>(T, conv_b, idx_i, out);
        k_final_new<<<1, 256, 0, stream>>>(hist, loss_s, zsq, out);
    } else {
        // ---- fallback: round-1 fp32 path ----
        float* ce2      = (float*)((char*)d_ws + WO_CE2);
        int*   hist     = (int*)((char*)d_ws + WO_HIST);
        float* loss_acc = (float*)((char*)d_ws + WO_LOSS);
        int*   idx_i    = (int*)((char*)d_ws + WO_IDX);
        float* T        = (float*)((char*)d_ws + WO_T);
        float* idx_f = out + OUT_ELEMS + 2;

        hipMemsetAsync(d_ws, 0, WO_TOTAL, stream);
        k_norms<<<NE, 64, 0, stream>>>(emb, ce2);
        k_wT<<<dim3(4, 16, 4), 256, 0, stream>>>(conv_w, emb, T);
        k_argmin<<<256, 256, 0, stream>>>(z, emb, ce2, idx_i, idx_f, hist, loss_acc);
        k_scatter<<<dim3(64, 16), 256, 0, stream>>>(T, conv_b, idx_i, out);
        k_final_old<<<1, 256, 0, stream>>>(hist, loss_acc, out);
    }
}

// Round 15
// 249.441 us; speedup vs baseline: 1.0509x; 1.0509x over previous
//
#include <hip/hip_runtime.h>
#include <math.h>

#define NE 256
#define EDIM 1024
#define HW 1024
#define NPIX 16384
#define OUT_ELEMS 16777216

typedef short short8 __attribute__((ext_vector_type(8)));
typedef float f32x4 __attribute__((ext_vector_type(4)));

// ---------------- fast-path workspace layout (bytes) ----------------
#define WS_HIST   0          // int[256]
#define WS_LOSS   1024       // float
#define WS_ZSQ    1028       // float
#define WS_FBITS  2048       // uint[512] bitmap of tie-flagged pixels (2 KB)
#define WS_T      4096       // float[1024*256] = 1 MB
#define WS_MEMSET 1052672
#define WS_ZERO_N4 65792     // WS_MEMSET / 16
// [no-init region]
#define WS_CE2    1052672    // float[256]
#define WS_IDX    1053696    // int[16384]
#define WS_EH     1119232    // ushort[256*1024] = 512 KB (bf16 high)
#define WS_EL     1643520    // ushort[256*1024] = 512 KB (bf16 residual)
#define WS_NEED   2167808

#define DELTA 0.02f          // tie-guard; bf16x3 score sigma ~2.5e-4 -> ~80 sigma

// ---------------- fallback (round-1) workspace layout ----------------
#define WO_CE2  0
#define WO_HIST 1024
#define WO_LOSS 2048
#define WO_IDX  4096
#define WO_T    69632
#define WO_TOTAL 1118208

__device__ __forceinline__ unsigned short f2bf(float f) {
    unsigned u = __float_as_uint(f);
    unsigned r = u + 0x7FFFu + ((u >> 16) & 1u);   // RNE
    return (unsigned short)(r >> 16);
}
__device__ __forceinline__ float bf2f(unsigned short h) {
    return __uint_as_float(((unsigned)h) << 16);
}

// async global->LDS, 16 B per lane; lptr must be wave-uniform (HW adds lane*16)
__device__ __forceinline__ void stage16(const void* g, void* l) {
    __builtin_amdgcn_global_load_lds(
        (const __attribute__((address_space(1))) unsigned int*)g,
        (__attribute__((address_space(3))) unsigned int*)l, 16, 0, 0);
}

// ------- fused prep: emb -> eh/el bf16 split, ce2, AND workspace zeroing ---
// (replaces the hipMemsetAsync dispatch: 256 blocks x 64 thr grid-stride
// zero the [hist|loss|zsq|fbits|T] region; stream order guarantees
// completion before k_wT's atomics / k_dist's atomics run)
__global__ __launch_bounds__(64) void k_prep(const float* __restrict__ emb,
                                             unsigned short* __restrict__ eh,
                                             unsigned short* __restrict__ el,
                                             float* __restrict__ ce2,
                                             float4* __restrict__ zws) {
    int j = blockIdx.x;
    int l = threadIdx.x;
    for (int i = j * 64 + l; i < WS_ZERO_N4; i += 256 * 64)
        zws[i] = (float4){0.f, 0.f, 0.f, 0.f};
    const float* row = emb + ((size_t)j << 10);
    float s = 0.f;
    #pragma unroll
    for (int i = 0; i < 4; i++) {
        float4 v = *(const float4*)(row + l * 4 + 256 * i);
        s += v.x * v.x + v.y * v.y + v.z * v.z + v.w * v.w;
        unsigned short h0 = f2bf(v.x), h1 = f2bf(v.y), h2 = f2bf(v.z), h3 = f2bf(v.w);
        uint2 hp, lp;
        hp.x = (unsigned)h0 | ((unsigned)h1 << 16);
        hp.y = (unsigned)h2 | ((unsigned)h3 << 16);
        lp.x = (unsigned)f2bf(v.x - bf2f(h0)) | ((unsigned)f2bf(v.y - bf2f(h1)) << 16);
        lp.y = (unsigned)f2bf(v.z - bf2f(h2)) | ((unsigned)f2bf(v.w - bf2f(h3)) << 16);
        *(uint2*)(eh + ((size_t)j << 10) + l * 4 + 256 * i) = hp;
        *(uint2*)(el + ((size_t)j << 10) + l * 4 + 256 * i) = lp;
    }
    #pragma unroll
    for (int m = 32; m; m >>= 1) s += __shfl_down(s, m, 64);
    if (l == 0) ce2[j] = 0.5f * s;
}

// ---------------- T[o][j] = sum_c w[o][c]*emb[j][c] (split-K, atomics) ----
__global__ __launch_bounds__(256) void k_wT(const float* __restrict__ w,
                                            const float* __restrict__ emb,
                                            float* __restrict__ T) {
    __shared__ float wt[64 * 17];
    __shared__ float et[64 * 17];
    int t = threadIdx.x;
    int j0 = blockIdx.x * 64;
    int o0 = blockIdx.y * 64;
    int kb = blockIdx.z * 256;
    int to = t & 15, tj = t >> 4;
    float acc[4][4] = {};
    int lr = t >> 2, lk = (t & 3) * 4;
    for (int kk = kb; kk < kb + 256; kk += 16) {
        float4 wv = *(const float4*)(w + (size_t)(o0 + lr) * EDIM + kk + lk);
        float4 ev = *(const float4*)(emb + (size_t)(j0 + lr) * EDIM + kk + lk);
        __syncthreads();
        wt[lr * 17 + lk + 0] = wv.x; wt[lr * 17 + lk + 1] = wv.y;
        wt[lr * 17 + lk + 2] = wv.z; wt[lr * 17 + lk + 3] = wv.w;
        et[lr * 17 + lk + 0] = ev.x; et[lr * 17 + lk + 1] = ev.y;
        et[lr * 17 + lk + 2] = ev.z; et[lr * 17 + lk + 3] = ev.w;
        __syncthreads();
        #pragma unroll
        for (int k = 0; k < 16; k++) {
            float a[4], b[4];
            #pragma unroll
            for (int i = 0; i < 4; i++) a[i] = wt[(to * 4 + i) * 17 + k];
            #pragma unroll
            for (int i = 0; i < 4; i++) b[i] = et[(tj * 4 + i) * 17 + k];
            #pragma unroll
            for (int i = 0; i < 4; i++)
                #pragma unroll
                for (int jx = 0; jx < 4; jx++) acc[i][jx] += a[i] * b[jx];
        }
    }
    #pragma unroll
    for (int i = 0; i < 4; i++)
        #pragma unroll
        for (int jx = 0; jx < 4; jx++)
            atomicAdd(&T[(size_t)(o0 + to * 4 + i) * NE + j0 + tj * 4 + jx],
                      acc[i][jx]);
}

// ---------------- fused bf16x3 distance GEMM + argmin + tie-flagging -------
// v4 (verified 72.5 us): 256 blocks x 256 thr, 64 px/block, shared LDS
// staging + T3/T4 counted-vmcnt pipeline: 4 LDS chunk-buffers, depth-3
// prefetch, raw s_barrier + s_waitcnt vmcnt(32) -- never drains to 0 in the
// main loop. Per chunk per wave = exactly 16 vmem ops (8 stage16 + 8 z);
// vmcnt(32) completes chunk ck, leaves ck+1/ck+2 in flight. Conflict-free
// XOR swizzle (pre-swizzled global source slot ql, de-swizzled read sq).
__global__ __launch_bounds__(256) void k_dist(
        const float* __restrict__ z, const unsigned short* __restrict__ eh,
        const unsigned short* __restrict__ el,
        const float* __restrict__ ce2,
        int* __restrict__ idx_i, float* __restrict__ idx_f,
        int* __restrict__ hist, float* __restrict__ loss_s,
        float* __restrict__ zsq_acc, unsigned int* __restrict__ fbits) {
    __shared__ unsigned short sB[4][2][256 * 32];   // 4 bufs x (eh,el) x 32 KB = 128 KB
    int t = threadIdx.x;
    int lane = t & 63, w = t >> 6;
    int m = lane & 15, quad = lane >> 4;
    int px0 = blockIdx.x * 64;          // 64-px blocks never cross a batch image
    int b = px0 >> 10;
    const float* zp = z + (((size_t)b) << 20) + (px0 & 1023) + w * 16 + m;
    int sc = t >> 2, qp = t & 3;        // staging row-within-64 / physical slot
    int ql = qp ^ ((sc >> 1) & 3);      // pre-swizzled source slot

    f32x4 acc[16];
    #pragma unroll
    for (int nt = 0; nt < 16; nt++) acc[nt] = (f32x4){0.f, 0.f, 0.f, 0.f};

    float zv0[8], zv1[8], zv2[8], zv3[8];
    float zsq = 0.f;
    int sq = quad ^ ((m >> 1) & 3);     // de-swizzled read slot

#define STAGE(c, B) do {                                                        \
    int kk_ = (c) * 32;                                                         \
    _Pragma("unroll")                                                           \
    for (int i_ = 0; i_ < 4; i_++) {                                            \
        stage16(eh + (((size_t)(i_ * 64 + sc)) << 10) + kk_ + ql * 8,           \
                &sB[B][0][(i_ * 256 + w * 64) * 8]);                            \
        stage16(el + (((size_t)(i_ * 64 + sc)) << 10) + kk_ + ql * 8,           \
                &sB[B][1][(i_ * 256 + w * 64) * 8]);                            \
    } } while (0)

#define ZLOAD(c, ZV) do {                                                       \
    int kk_ = (c) * 32;                                                         \
    _Pragma("unroll")                                                           \
    for (int j_ = 0; j_ < 8; j_++)                                              \
        ZV[j_] = zp[((size_t)(kk_ + quad * 8 + j_)) << 10];                     \
    } while (0)

#define WAITV(n) do {                                                           \
    asm volatile("s_waitcnt vmcnt(" #n ")" ::: "memory");                       \
    __builtin_amdgcn_sched_barrier(0); } while (0)

#define FENCE() do {                                                            \
    asm volatile("" ::: "memory");                                              \
    __builtin_amdgcn_sched_barrier(0); } while (0)

#define BODY(c, B, ZV, PRE, B3, ZV3) do {                                       \
    __builtin_amdgcn_s_barrier();                                               \
    short8 ah, al;                                                              \
    _Pragma("unroll")                                                           \
    for (int j_ = 0; j_ < 8; j_++) {                                            \
        float zj_ = ZV[j_];                                                     \
        zsq += zj_ * zj_;                                                       \
        unsigned short h_ = f2bf(zj_);                                          \
        ((unsigned short*)&ah)[j_] = h_;                                        \
        ((unsigned short*)&al)[j_] = f2bf(zj_ - bf2f(h_));                      \
    }                                                                           \
    if (PRE) { STAGE((c) + 3, B3); ZLOAD((c) + 3, ZV3); }                       \
    _Pragma("unroll")                                                           \
    for (int nt_ = 0; nt_ < 16; nt_++) {                                        \
        short8 bh_ = *(const short8*)&sB[B][0][(nt_ * 16 + m) * 32 + sq * 8];   \
        short8 bl_ = *(const short8*)&sB[B][1][(nt_ * 16 + m) * 32 + sq * 8];   \
        acc[nt_] = __builtin_amdgcn_mfma_f32_16x16x32_bf16(ah, bh_, acc[nt_], 0, 0, 0); \
        acc[nt_] = __builtin_amdgcn_mfma_f32_16x16x32_bf16(ah, bl_, acc[nt_], 0, 0, 0); \
        acc[nt_] = __builtin_amdgcn_mfma_f32_16x16x32_bf16(al, bh_, acc[nt_], 0, 0, 0); \
    } } while (0)

    // prologue: chunks 0,1,2 in flight (order pinned by fences -> 48 ops)
    STAGE(0, 0); ZLOAD(0, zv0); FENCE();
    STAGE(1, 1); ZLOAD(1, zv1); FENCE();
    STAGE(2, 2); ZLOAD(2, zv2);

    // main loop: ck = 0..27; steady-state 48 outstanding at each WAITV
    for (int mi = 0; mi < 7; mi++) {
        WAITV(32); BODY(mi * 4 + 0, 0, zv0, 1, 3, zv3);
        WAITV(32); BODY(mi * 4 + 1, 1, zv1, 1, 0, zv0);
        WAITV(32); BODY(mi * 4 + 2, 2, zv2, 1, 1, zv1);
        WAITV(32); BODY(mi * 4 + 3, 3, zv3, 1, 2, zv2);
    }
    // tail: ck=28 issues 31; then drain 32 -> 16 -> 0
    WAITV(32); BODY(28, 0, zv0, 1, 3, zv3);
    WAITV(32); BODY(29, 1, zv1, 0, 2, zv2);
    WAITV(16); BODY(30, 2, zv2, 0, 3, zv3);
    WAITV(0);  BODY(31, 3, zv3, 0, 0, zv0);

#undef STAGE
#undef ZLOAD
#undef WAITV
#undef FENCE
#undef BODY

    // zsq: waves cover disjoint px, full K each
    #pragma unroll
    for (int msk = 32; msk; msk >>= 1) zsq += __shfl_down(zsq, msk, 64);
    if (lane == 0) atomicAdd(zsq_acc, zsq);

    // ----- per-wave epilogue: argmin over 256 codes for 16 px -----
    float c2v[16];
    #pragma unroll
    for (int nt = 0; nt < 16; nt++) c2v[nt] = ce2[nt * 16 + m];

    float lsum = 0.f;
    #pragma unroll
    for (int r = 0; r < 4; r++) {        // D layout: px row = quad*4+r, code col = m
        float v1 = 3.4e38f, v2 = 3.4e38f; int i1 = 0;
        #pragma unroll
        for (int nt = 0; nt < 16; nt++) {
            int code = nt * 16 + m;
            float sv = c2v[nt] - acc[nt][r];   // 0.5||e||^2 - z.e
            if (sv < v1 || (sv == v1 && code < i1)) { v2 = v1; v1 = sv; i1 = code; }
            else v2 = fminf(v2, sv);
        }
        #pragma unroll
        for (int msk = 1; msk < 16; msk <<= 1) {
            float ov1 = __shfl_xor(v1, msk, 64);
            int   oi1 = __shfl_xor(i1, msk, 64);
            float ov2 = __shfl_xor(v2, msk, 64);
            float nv2 = fminf(fminf(v2, ov2), fmaxf(v1, ov1));
            if (ov1 < v1 || (ov1 == v1 && oi1 < i1)) { v1 = ov1; i1 = oi1; }
            v2 = nv2;
        }
        if (m == 0) {
            int px = px0 + w * 16 + quad * 4 + r;
            idx_i[px] = i1;
            idx_f[px] = (float)i1;
            atomicAdd(&hist[i1], 1);
            if (v2 - v1 < DELTA)
                atomicOr(&fbits[px >> 5], 1u << (px & 31));
            lsum += v1;
        }
    }
    lsum += __shfl_xor(lsum, 16, 64);
    lsum += __shfl_xor(lsum, 32, 64);
    if (lane == 0) atomicAdd(loss_s, lsum);
}

// ---------------- exact fp32 re-argmin for tie-flagged pixels --------------
__global__ __launch_bounds__(256) void k_cleanup(const float* __restrict__ z,
        const float* __restrict__ emb, const float* __restrict__ ce2,
        const unsigned int* __restrict__ fbits,
        int* __restrict__ idx_i, float* __restrict__ idx_f, int* __restrict__ hist) {
    __shared__ float zs[1024];
    __shared__ float rv[4];
    __shared__ int ri[4];
    int t = threadIdx.x;
    const float* er = emb + (size_t)t * EDIM;
    for (int px = blockIdx.x; px < NPIX; px += gridDim.x) {
        if (!(fbits[px >> 5] & (1u << (px & 31)))) continue;   // uniform per block
        int b = px >> 10, p = px & 1023;
        const float* zb = z + (((size_t)b) << 20) + p;
        #pragma unroll
        for (int r = 0; r < 4; r++) {
            int c = t + 256 * r;
            zs[c] = zb[((size_t)c) << 10];
        }
        __syncthreads();
        float d0 = 0.f, d1 = 0.f, d2 = 0.f, d3 = 0.f;
        #pragma unroll 4
        for (int c = 0; c < EDIM; c += 16) {
            float4 e0 = *(const float4*)(er + c);
            float4 e1 = *(const float4*)(er + c + 4);
            float4 e2 = *(const float4*)(er + c + 8);
            float4 e3 = *(const float4*)(er + c + 12);
            d0 += e0.x * zs[c]      + e0.y * zs[c + 1]  + e0.z * zs[c + 2]  + e0.w * zs[c + 3];
            d1 += e1.x * zs[c + 4]  + e1.y * zs[c + 5]  + e1.z * zs[c + 6]  + e1.w * zs[c + 7];
            d2 += e2.x * zs[c + 8]  + e2.y * zs[c + 9]  + e2.z * zs[c + 10] + e2.w * zs[c + 11];
            d3 += e3.x * zs[c + 12] + e3.y * zs[c + 13] + e3.z * zs[c + 14] + e3.w * zs[c + 15];
        }
        float sv = ce2[t] - ((d0 + d1) + (d2 + d3));
        int bi = t;
        #pragma unroll
        for (int msk = 1; msk < 64; msk <<= 1) {
            float ov = __shfl_xor(sv, msk, 64);
            int oi = __shfl_xor(bi, msk, 64);
            if (ov < sv || (ov == sv && oi < bi)) { sv = ov; bi = oi; }
        }
        if ((t & 63) == 0) { rv[t >> 6] = sv; ri[t >> 6] = bi; }
        __syncthreads();
        if (t == 0) {
            float v = rv[0]; int ix = ri[0];
            for (int ww = 1; ww < 4; ww++)
                if (rv[ww] < v || (rv[ww] == v && ri[ww] < ix)) { v = rv[ww]; ix = ri[ww]; }
            int old = idx_i[px];
            if (ix != old) {
                idx_i[px] = ix; idx_f[px] = (float)ix;
                atomicAdd(&hist[ix], 1); atomicSub(&hist[old], 1);
            }
        }
        __syncthreads();
    }
}

// ---------------- round-1 fp32 argmin (fallback only) ----------------------
__global__ __launch_bounds__(64) void k_norms(const float* __restrict__ emb,
                                              float* __restrict__ ce2) {
    int j = blockIdx.x;
    int lane = threadIdx.x;
    const float* row = emb + (size_t)j * EDIM;
    float s = 0.f;
    #pragma unroll
    for (int i = 0; i < EDIM / 64; i++) {
        float v = row[lane + 64 * i];
        s += v * v;
    }
    #pragma unroll
    for (int m = 32; m; m >>= 1) s += __shfl_down(s, m, 64);
    if (lane == 0) ce2[j] = 0.5f * s;
}

__global__ __launch_bounds__(256) void k_argmin(const float* __restrict__ z,
                                                const float* __restrict__ emb,
                                                const float* __restrict__ ce2,
                                                int* __restrict__ idx_i,
                                                float* __restrict__ idx_f,
                                                int* __restrict__ hist,
                                                float* __restrict__ loss_acc) {
    __shared__ float zt[32 * 64];
    __shared__ float et[256 * 34];
    __shared__ float znorm_s[64];
    int t = threadIdx.x;
    int n0 = blockIdx.x * 64;
    int b = n0 >> 10;
    int p0 = n0 & 1023;
    const float* zb = z + (size_t)b * EDIM * HW;
    int tc = t & 31, tp = t >> 5;
    float acc[8][8] = {};
    float znorm = 0.f;
    for (int kk = 0; kk < EDIM; kk += 32) {
        #pragma unroll
        for (int i = 0; i < 16; i++) {
            int q = t + 256 * i;
            int code = q >> 4, k2 = q & 15;
            float2 v = *(const float2*)(emb + (size_t)code * EDIM + kk + k2 * 2);
            *(float2*)(et + code * 34 + k2 * 2) = v;
        }
        #pragma unroll
        for (int i = 0; i < 4; i++) {
            int q = t + 256 * i;
            int k = q >> 5, p2 = q & 31;
            float2 v = *(const float2*)(zb + (size_t)(kk + k) * HW + p0 + p2 * 2);
            *(float2*)(zt + k * 64 + p2 * 2) = v;
        }
        __syncthreads();
        if (t < 64) {
            #pragma unroll
            for (int k = 0; k < 32; k++) { float zz = zt[k * 64 + t]; znorm += zz * zz; }
        }
        #pragma unroll 4
        for (int k2 = 0; k2 < 16; k2++) {
            float2 ev[8], za[4], zb2[4];
            #pragma unroll
            for (int u = 0; u < 8; u++)
                ev[u] = *(float2*)(et + (tc + 32 * u) * 34 + k2 * 2);
            #pragma unroll
            for (int j = 0; j < 4; j++)
                za[j] = *(float2*)(zt + (2 * k2) * 64 + tp * 8 + 2 * j);
            #pragma unroll
            for (int j = 0; j < 4; j++)
                zb2[j] = *(float2*)(zt + (2 * k2 + 1) * 64 + tp * 8 + 2 * j);
            #pragma unroll
            for (int p = 0; p < 8; p++) {
                float z0 = (p & 1) ? za[p >> 1].y : za[p >> 1].x;
                float z1 = (p & 1) ? zb2[p >> 1].y : zb2[p >> 1].x;
                #pragma unroll
                for (int u = 0; u < 8; u++)
                    acc[p][u] += z0 * ev[u].x + z1 * ev[u].y;
            }
        }
        __syncthreads();
    }
    if (t < 64) znorm_s[t] = znorm;
    float minv[8];
    int mini[8];
    #pragma unroll
    for (int p = 0; p < 8; p++) { minv[p] = 3.4e38f; mini[p] = 0; }
    #pragma unroll
    for (int u = 0; u < 8; u++) {
        int code = tc + 32 * u;
        float cc2 = ce2[code];
        #pragma unroll
        for (int p = 0; p < 8; p++) {
            float s = cc2 - acc[p][u];
            if (s < minv[p] || (s == minv[p] && code < mini[p])) { minv[p] = s; mini[p] = code; }
        }
    }
    #pragma unroll
    for (int m = 1; m < 32; m <<= 1) {
        #pragma unroll
        for (int p = 0; p < 8; p++) {
            float ov = __shfl_xor(minv[p], m, 64);
            int oi = __shfl_xor(mini[p], m, 64);
            if (ov < minv[p] || (ov == minv[p] && oi < mini[p])) { minv[p] = ov; mini[p] = oi; }
        }
    }
    __syncthreads();
    if (tc == 0) {
        float dsum = 0.f;
        #pragma unroll
        for (int p = 0; p < 8; p++) {
            int lp = tp * 8 + p;
            int n = n0 + lp;
            idx_i[n] = mini[p];
            idx_f[n] = (float)mini[p];
            dsum += znorm_s[lp] + 2.f * minv[p];
            atomicAdd(&hist[mini[p]], 1);
        }
        atomicAdd(loss_acc, dsum);
    }
}

// ------ out[b][o][p] = T[o][idx[b][p]] + bias[o], + fused finalize --------
// Block (0,0) additionally computes loss/perplexity (hist/loss_s/zsq are
// complete before this kernel launches -- stream-ordered after k_cleanup).
__global__ __launch_bounds__(256) void k_scatter_f(const float* __restrict__ T,
                                                   const float* __restrict__ bias,
                                                   const int* __restrict__ idx,
                                                   const int* __restrict__ hist,
                                                   const float* __restrict__ loss_s,
                                                   const float* __restrict__ zsq,
                                                   float* __restrict__ out) {
    __shared__ float Ts[16 * 256];
    __shared__ float bs[16];
    __shared__ float red[4];
    int t = threadIdx.x;
    int o0 = blockIdx.x * 16;
    int b = blockIdx.y;
    #pragma unroll
    for (int r = 0; r < 16; r++)
        Ts[r * 256 + t] = T[(size_t)(o0 + r) * NE + t];
    if (t < 16) bs[t] = bias[o0 + t];
    __syncthreads();
    int4 i4 = *(const int4*)(idx + b * HW + t * 4);
    #pragma unroll
    for (int r = 0; r < 16; r++) {
        const float* Tr = Ts + r * 256;
        float bb = bs[r];
        float4 v;
        v.x = Tr[i4.x] + bb;
        v.y = Tr[i4.y] + bb;
        v.z = Tr[i4.z] + bb;
        v.w = Tr[i4.w] + bb;
        *(float4*)(out + ((size_t)(b * EDIM + o0 + r) * HW) + t * 4) = v;
    }
    if (blockIdx.x == 0 && blockIdx.y == 0) {
        float em = (float)hist[t] * (1.0f / 16384.0f);
        float v = em * logf(em + 1e-10f);
        #pragma unroll
        for (int m = 32; m; m >>= 1) v += __shfl_down(v, m, 64);
        if ((t & 63) == 0) red[t >> 6] = v;
        __syncthreads();
        if (t == 0) {
            float s = red[0] + red[1] + red[2] + red[3];
            out[OUT_ELEMS] = (zsq[0] + 2.f * loss_s[0]) * 1.25f / 16777216.f;
            out[OUT_ELEMS + 1] = expf(-s);
        }
    }
}

// ---------------- fallback scatter + finalize ------------------------------
__global__ __launch_bounds__(256) void k_scatter(const float* __restrict__ T,
                                                 const float* __restrict__ bias,
                                                 const int* __restrict__ idx,
                                                 float* __restrict__ out) {
    __shared__ float Ts[16 * 256];
    __shared__ float bs[16];
    int t = threadIdx.x;
    int o0 = blockIdx.x * 16;
    int b = blockIdx.y;
    #pragma unroll
    for (int r = 0; r < 16; r++)
        Ts[r * 256 + t] = T[(size_t)(o0 + r) * NE + t];
    if (t < 16) bs[t] = bias[o0 + t];
    __syncthreads();
    int4 i4 = *(const int4*)(idx + b * HW + t * 4);
    #pragma unroll
    for (int r = 0; r < 16; r++) {
        const float* Tr = Ts + r * 256;
        float bb = bs[r];
        float4 v;
        v.x = Tr[i4.x] + bb;
        v.y = Tr[i4.y] + bb;
        v.z = Tr[i4.z] + bb;
        v.w = Tr[i4.w] + bb;
        *(float4*)(out + ((size_t)(b * EDIM + o0 + r) * HW) + t * 4) = v;
    }
}

__global__ __launch_bounds__(256) void k_final_old(const int* __restrict__ hist,
                                                   const float* __restrict__ loss_acc,
                                                   float* __restrict__ out) {
    __shared__ float red[4];
    int t = threadIdx.x;
    float em = (float)hist[t] * (1.0f / 16384.0f);
    float v = em * logf(em + 1e-10f);
    #pragma unroll
    for (int m = 32; m; m >>= 1) v += __shfl_down(v, m, 64);
    if ((t & 63) == 0) red[t >> 6] = v;
    __syncthreads();
    if (t == 0) {
        float s = red[0] + red[1] + red[2] + red[3];
        out[OUT_ELEMS] = loss_acc[0] * 1.25f / 16777216.f;
        out[OUT_ELEMS + 1] = expf(-s);
    }
}

extern "C" void kernel_launch(void* const* d_in, const int* in_sizes, int n_in,
                              void* d_out, int out_size, void* d_ws, size_t ws_size,
                              hipStream_t stream) {
    (void)in_sizes; (void)n_in; (void)out_size;
    const float* z      = (const float*)d_in[0];
    const float* emb    = (const float*)d_in[1];
    const float* conv_w = (const float*)d_in[2];
    const float* conv_b = (const float*)d_in[3];
    float* out = (float*)d_out;

    if (ws_size >= WS_NEED) {
        // ---- fast path: 5 dispatches (zeroing fused into prep, final into
        // scatter); k_dist = verified v4 counted-vmcnt pipeline ----
        int*   hist     = (int*)((char*)d_ws + WS_HIST);
        float* loss_s   = (float*)((char*)d_ws + WS_LOSS);
        float* zsq      = (float*)((char*)d_ws + WS_ZSQ);
        unsigned int* fbits = (unsigned int*)((char*)d_ws + WS_FBITS);
        float* T        = (float*)((char*)d_ws + WS_T);
        float* ce2      = (float*)((char*)d_ws + WS_CE2);
        int*   idx_i    = (int*)((char*)d_ws + WS_IDX);
        unsigned short* eh = (unsigned short*)((char*)d_ws + WS_EH);
        unsigned short* el = (unsigned short*)((char*)d_ws + WS_EL);
        float* idx_f = out + OUT_ELEMS + 2;

        k_prep<<<NE, 64, 0, stream>>>(emb, eh, el, ce2, (float4*)d_ws);
        k_wT<<<dim3(4, 16, 4), 256, 0, stream>>>(conv_w, emb, T);
        k_dist<<<256, 256, 0, stream>>>(z, eh, el, ce2, idx_i, idx_f,
                                        hist, loss_s, zsq, fbits);
        k_cleanup<<<256, 256, 0, stream>>>(z, emb, ce2, fbits, idx_i, idx_f, hist);
        k_scatter_f<<<dim3(64, 16), 256, 0, stream>>>(T, conv_b, idx_i,
                                                      hist, loss_s, zsq, out);
    } else {
        // ---- fallback: round-1 fp32 path ----
        float* ce2      = (float*)((char*)d_ws + WO_CE2);
        int*   hist     = (int*)((char*)d_ws + WO_HIST);
        float* loss_acc = (float*)((char*)d_ws + WO_LOSS);
        int*   idx_i    = (int*)((char*)d_ws + WO_IDX);
        float* T        = (float*)((char*)d_ws + WO_T);
        float* idx_f = out + OUT_ELEMS + 2;

        hipMemsetAsync(d_ws, 0, WO_TOTAL, stream);
        k_norms<<<NE, 64, 0, stream>>>(emb, ce2);
        k_wT<<<dim3(4, 16, 4), 256, 0, stream>>>(conv_w, emb, T);
        k_argmin<<<256, 256, 0, stream>>>(z, emb, ce2, idx_i, idx_f, hist, loss_acc);
        k_scatter<<<dim3(64, 16), 256, 0, stream>>>(T, conv_b, idx_i, out);
        k_final_old<<<1, 256, 0, stream>>>(hist, loss_acc, out);
    }
}

// Round 17
// 244.180 us; speedup vs baseline: 1.0735x; 1.0215x over previous
//
#include <hip/hip_runtime.h>
#include <math.h>

#define NE 256
#define EDIM 1024
#define HW 1024
#define NPIX 16384
#define OUT_ELEMS 16777216

typedef short short8 __attribute__((ext_vector_type(8)));
typedef float f32x4 __attribute__((ext_vector_type(4)));

// ---------------- fast-path workspace layout (bytes) ----------------
#define WS_HIST   0          // int[256]
#define WS_LOSS   1024       // float
#define WS_ZSQ    1028       // float
#define WS_FBITS  2048       // uint[512] bitmap of tie-flagged pixels (2 KB)
#define WS_T      4096       // float[1024*256] = 1 MB
#define WS_MEMSET 1052672
#define WS_ZERO_N4 65792     // WS_MEMSET / 16
// [no-init region]
#define WS_CE2    1052672    // float[256]
#define WS_IDX    1053696    // int[16384]
#define WS_EH     1119232    // ushort[256*1024] = 512 KB (bf16 high)
#define WS_EL     1643520    // ushort[256*1024] = 512 KB (bf16 residual)
#define WS_NEED   2167808

#define DELTA 0.02f          // tie-guard; bf16x3 score sigma ~2.5e-4 -> ~80 sigma

// ---------------- fallback (round-1) workspace layout ----------------
#define WO_CE2  0
#define WO_HIST 1024
#define WO_LOSS 2048
#define WO_IDX  4096
#define WO_T    69632
#define WO_TOTAL 1118208

__device__ __forceinline__ unsigned short f2bf(float f) {
    unsigned u = __float_as_uint(f);
    unsigned r = u + 0x7FFFu + ((u >> 16) & 1u);   // RNE
    return (unsigned short)(r >> 16);
}
__device__ __forceinline__ float bf2f(unsigned short h) {
    return __uint_as_float(((unsigned)h) << 16);
}

// async global->LDS, 16 B per lane; lptr must be wave-uniform (HW adds lane*16)
__device__ __forceinline__ void stage16(const void* g, void* l) {
    __builtin_amdgcn_global_load_lds(
        (const __attribute__((address_space(1))) unsigned int*)g,
        (__attribute__((address_space(3))) unsigned int*)l, 16, 0, 0);
}

// ------- fused prep: emb -> eh/el bf16 split, ce2, AND workspace zeroing ---
__global__ __launch_bounds__(64) void k_prep(const float* __restrict__ emb,
                                             unsigned short* __restrict__ eh,
                                             unsigned short* __restrict__ el,
                                             float* __restrict__ ce2,
                                             float4* __restrict__ zws) {
    int j = blockIdx.x;
    int l = threadIdx.x;
    for (int i = j * 64 + l; i < WS_ZERO_N4; i += 256 * 64)
        zws[i] = (float4){0.f, 0.f, 0.f, 0.f};
    const float* row = emb + ((size_t)j << 10);
    float s = 0.f;
    #pragma unroll
    for (int i = 0; i < 4; i++) {
        float4 v = *(const float4*)(row + l * 4 + 256 * i);
        s += v.x * v.x + v.y * v.y + v.z * v.z + v.w * v.w;
        unsigned short h0 = f2bf(v.x), h1 = f2bf(v.y), h2 = f2bf(v.z), h3 = f2bf(v.w);
        uint2 hp, lp;
        hp.x = (unsigned)h0 | ((unsigned)h1 << 16);
        hp.y = (unsigned)h2 | ((unsigned)h3 << 16);
        lp.x = (unsigned)f2bf(v.x - bf2f(h0)) | ((unsigned)f2bf(v.y - bf2f(h1)) << 16);
        lp.y = (unsigned)f2bf(v.z - bf2f(h2)) | ((unsigned)f2bf(v.w - bf2f(h3)) << 16);
        *(uint2*)(eh + ((size_t)j << 10) + l * 4 + 256 * i) = hp;
        *(uint2*)(el + ((size_t)j << 10) + l * 4 + 256 * i) = lp;
    }
    #pragma unroll
    for (int m = 32; m; m >>= 1) s += __shfl_down(s, m, 64);
    if (l == 0) ce2[j] = 0.5f * s;
}

// ---------------- T[o][j] = sum_c w[o][c]*emb[j][c] (split-K, atomics) ----
__global__ __launch_bounds__(256) void k_wT(const float* __restrict__ w,
                                            const float* __restrict__ emb,
                                            float* __restrict__ T) {
    __shared__ float wt[64 * 17];
    __shared__ float et[64 * 17];
    int t = threadIdx.x;
    int j0 = blockIdx.x * 64;
    int o0 = blockIdx.y * 64;
    int kb = blockIdx.z * 256;
    int to = t & 15, tj = t >> 4;
    float acc[4][4] = {};
    int lr = t >> 2, lk = (t & 3) * 4;
    for (int kk = kb; kk < kb + 256; kk += 16) {
        float4 wv = *(const float4*)(w + (size_t)(o0 + lr) * EDIM + kk + lk);
        float4 ev = *(const float4*)(emb + (size_t)(j0 + lr) * EDIM + kk + lk);
        __syncthreads();
        wt[lr * 17 + lk + 0] = wv.x; wt[lr * 17 + lk + 1] = wv.y;
        wt[lr * 17 + lk + 2] = wv.z; wt[lr * 17 + lk + 3] = wv.w;
        et[lr * 17 + lk + 0] = ev.x; et[lr * 17 + lk + 1] = ev.y;
        et[lr * 17 + lk + 2] = ev.z; et[lr * 17 + lk + 3] = ev.w;
        __syncthreads();
        #pragma unroll
        for (int k = 0; k < 16; k++) {
            float a[4], b[4];
            #pragma unroll
            for (int i = 0; i < 4; i++) a[i] = wt[(to * 4 + i) * 17 + k];
            #pragma unroll
            for (int i = 0; i < 4; i++) b[i] = et[(tj * 4 + i) * 17 + k];
            #pragma unroll
            for (int i = 0; i < 4; i++)
                #pragma unroll
                for (int jx = 0; jx < 4; jx++) acc[i][jx] += a[i] * b[jx];
        }
    }
    #pragma unroll
    for (int i = 0; i < 4; i++)
        #pragma unroll
        for (int jx = 0; jx < 4; jx++)
            atomicAdd(&T[(size_t)(o0 + to * 4 + i) * NE + j0 + tj * 4 + jx],
                      acc[i][jx]);
}

// ---------------- fused bf16x3 distance GEMM + argmin + tie-flagging -------
// v8: v4's pipeline at 2 waves/SIMD. 256 blocks x 512 thr; block = 64 px.
// 8 waves: wave w = (px-tile pt=w>>1, code-half ch=w&1). Per wave per chunk:
// 4 stage16 (32 KB staged ONCE per block -- no extra stage traffic vs v4)
// + 8 z dwords (z and f2bf duplicated 2x across the code-half pair; bounded
// cost, VALU was only 13% busy) + 16 ds_read_b128 + 24 MFMA. Depth-3
// counted-vmcnt pipeline: 12 vmem/chunk/wave -> WAITV(24) steady (36
// outstanding), tail 24/12/0. Same conflict-free XOR swizzle (staging map:
// row=w*32+(lane>>2), ql=(lane&3)^((row>>1)&3); read sq=quad^((m>>1)&3)).
// Cross-half argmin merge via 0.75 KB LDS (ties -> half0 = lower code).
__global__ __launch_bounds__(512) void k_dist(
        const float* __restrict__ z, const unsigned short* __restrict__ eh,
        const unsigned short* __restrict__ el,
        const float* __restrict__ ce2,
        int* __restrict__ idx_i, float* __restrict__ idx_f,
        int* __restrict__ hist, float* __restrict__ loss_s,
        float* __restrict__ zsq_acc, unsigned int* __restrict__ fbits) {
    __shared__ unsigned short sB[4][2][256 * 32];   // 4 bufs x (eh,el) x 32 KB = 128 KB
    __shared__ float v1h[64], v2h[64];
    __shared__ int   i1h[64];
    int t = threadIdx.x;
    int lane = t & 63, w = t >> 6;       // 8 waves
    int m = lane & 15, quad = lane >> 4;
    int pt = w >> 1, ch = w & 1;         // px-tile / code-half
    int c_base = ch << 7;
    int px0 = blockIdx.x * 64;           // 64-px blocks never cross an image
    int b = px0 >> 10;
    const float* zp = z + (((size_t)b) << 20) + (px0 & 1023) + pt * 16 + m;
    int sr0 = w * 32 + (lane >> 2);      // staging row (instr 0); instr 1 = +16
    int qsl = (lane & 3) ^ ((sr0 >> 1) & 3);   // pre-swizzled slot (same for +16)

    f32x4 acc[8];
    #pragma unroll
    for (int nt = 0; nt < 8; nt++) acc[nt] = (f32x4){0.f, 0.f, 0.f, 0.f};

    float zv0[8], zv1[8], zv2[8], zv3[8];
    float zsq = 0.f;
    int sq = quad ^ ((m >> 1) & 3);      // de-swizzled read slot

#define STAGE(c, B) do {                                                        \
    int kk_ = (c) * 32;                                                         \
    stage16(eh + (((size_t)sr0) << 10) + kk_ + qsl * 8,                         \
            &sB[B][0][(w * 2) * 64 * 8]);                                       \
    stage16(el + (((size_t)sr0) << 10) + kk_ + qsl * 8,                         \
            &sB[B][1][(w * 2) * 64 * 8]);                                       \
    stage16(eh + (((size_t)(sr0 + 16)) << 10) + kk_ + qsl * 8,                  \
            &sB[B][0][(w * 2 + 1) * 64 * 8]);                                   \
    stage16(el + (((size_t)(sr0 + 16)) << 10) + kk_ + qsl * 8,                  \
            &sB[B][1][(w * 2 + 1) * 64 * 8]);                                   \
    } while (0)

#define ZLOAD(c, ZV) do {                                                       \
    int kk_ = (c) * 32;                                                         \
    _Pragma("unroll")                                                           \
    for (int j_ = 0; j_ < 8; j_++)                                              \
        ZV[j_] = zp[((size_t)(kk_ + quad * 8 + j_)) << 10];                     \
    } while (0)

#define WAITV(n) do {                                                           \
    asm volatile("s_waitcnt vmcnt(" #n ")" ::: "memory");                       \
    __builtin_amdgcn_sched_barrier(0); } while (0)

#define FENCE() do {                                                            \
    asm volatile("" ::: "memory");                                              \
    __builtin_amdgcn_sched_barrier(0); } while (0)

#define BODY(c, B, ZV, PRE, B3, ZV3) do {                                       \
    __builtin_amdgcn_s_barrier();                                               \
    short8 ah, al;                                                              \
    _Pragma("unroll")                                                           \
    for (int j_ = 0; j_ < 8; j_++) {                                            \
        float zj_ = ZV[j_];                                                     \
        zsq += zj_ * zj_;                                                       \
        unsigned short h_ = f2bf(zj_);                                          \
        ((unsigned short*)&ah)[j_] = h_;                                        \
        ((unsigned short*)&al)[j_] = f2bf(zj_ - bf2f(h_));                      \
    }                                                                           \
    if (PRE) { STAGE((c) + 3, B3); ZLOAD((c) + 3, ZV3); }                       \
    _Pragma("unroll")                                                           \
    for (int nt_ = 0; nt_ < 8; nt_++) {                                         \
        int crow_ = (c_base + nt_ * 16 + m) * 32;                               \
        short8 bh_ = *(const short8*)&sB[B][0][crow_ + sq * 8];                 \
        short8 bl_ = *(const short8*)&sB[B][1][crow_ + sq * 8];                 \
        acc[nt_] = __builtin_amdgcn_mfma_f32_16x16x32_bf16(ah, bh_, acc[nt_], 0, 0, 0); \
        acc[nt_] = __builtin_amdgcn_mfma_f32_16x16x32_bf16(ah, bl_, acc[nt_], 0, 0, 0); \
        acc[nt_] = __builtin_amdgcn_mfma_f32_16x16x32_bf16(al, bh_, acc[nt_], 0, 0, 0); \
    } } while (0)

    // prologue: chunks 0,1,2 in flight (order pinned -> 36 outstanding)
    STAGE(0, 0); ZLOAD(0, zv0); FENCE();
    STAGE(1, 1); ZLOAD(1, zv1); FENCE();
    STAGE(2, 2); ZLOAD(2, zv2);

    // main loop: ck = 0..27; steady-state 36 outstanding at each WAITV
    for (int mi = 0; mi < 7; mi++) {
        WAITV(24); BODY(mi * 4 + 0, 0, zv0, 1, 3, zv3);
        WAITV(24); BODY(mi * 4 + 1, 1, zv1, 1, 0, zv0);
        WAITV(24); BODY(mi * 4 + 2, 2, zv2, 1, 1, zv1);
        WAITV(24); BODY(mi * 4 + 3, 3, zv3, 1, 2, zv2);
    }
    // tail: ck=28 issues 31; then drain 24 -> 12 -> 0
    WAITV(24); BODY(28, 0, zv0, 1, 3, zv3);
    WAITV(24); BODY(29, 1, zv1, 0, 2, zv2);
    WAITV(12); BODY(30, 2, zv2, 0, 3, zv3);
    WAITV(0);  BODY(31, 3, zv3, 0, 0, zv0);

#undef STAGE
#undef ZLOAD
#undef WAITV
#undef FENCE
#undef BODY

    // zsq: ch==0 waves cover the 64 px exactly once, full K
    #pragma unroll
    for (int msk = 32; msk; msk >>= 1) zsq += __shfl_down(zsq, msk, 64);
    if (ch == 0 && lane == 0) atomicAdd(zsq_acc, zsq);

    // ----- per-wave argmin over its 128 codes for its 16 px -----
    float c2v[8];
    #pragma unroll
    for (int nt = 0; nt < 8; nt++) c2v[nt] = ce2[c_base + nt * 16 + m];

    float v1r[4], v2r[4];
    int i1r[4];
    #pragma unroll
    for (int r = 0; r < 4; r++) {        // D layout: px row = quad*4+r, code col = m
        float v1 = 3.4e38f, v2 = 3.4e38f; int i1 = 0;
        #pragma unroll
        for (int nt = 0; nt < 8; nt++) {
            int code = c_base + nt * 16 + m;
            float sv = c2v[nt] - acc[nt][r];   // 0.5||e||^2 - z.e
            if (sv < v1 || (sv == v1 && code < i1)) { v2 = v1; v1 = sv; i1 = code; }
            else v2 = fminf(v2, sv);
        }
        #pragma unroll
        for (int msk = 1; msk < 16; msk <<= 1) {
            float ov1 = __shfl_xor(v1, msk, 64);
            int   oi1 = __shfl_xor(i1, msk, 64);
            float ov2 = __shfl_xor(v2, msk, 64);
            float nv2 = fminf(fminf(v2, ov2), fmaxf(v1, ov1));
            if (ov1 < v1 || (ov1 == v1 && oi1 < i1)) { v1 = ov1; i1 = oi1; }
            v2 = nv2;
        }
        v1r[r] = v1; v2r[r] = v2; i1r[r] = i1;
    }
    int pxl = pt * 16 + quad * 4;        // block-local px base for this lane col
    if (ch == 0 && m == 0) {
        #pragma unroll
        for (int r = 0; r < 4; r++) {
            v1h[pxl + r] = v1r[r]; v2h[pxl + r] = v2r[r]; i1h[pxl + r] = i1r[r];
        }
    }
    __syncthreads();
    if (ch == 1) {
        float lsum = 0.f;
        if (m == 0) {
            #pragma unroll
            for (int r = 0; r < 4; r++) {
                int pl = pxl + r;
                float va = v1h[pl], v2a = v2h[pl];
                int   ia = i1h[pl];
                float vb = v1r[r];
                float v2m = fminf(fminf(v2a, v2r[r]), fmaxf(va, vb));
                float v1; int i1;
                if (vb < va) { v1 = vb; i1 = i1r[r]; }   // ties -> half0 (lower code)
                else         { v1 = va; i1 = ia; }
                int px = px0 + pl;
                idx_i[px] = i1;
                idx_f[px] = (float)i1;
                atomicAdd(&hist[i1], 1);
                if (v2m - v1 < DELTA)
                    atomicOr(&fbits[px >> 5], 1u << (px & 31));
                lsum += v1;
            }
        }
        lsum += __shfl_xor(lsum, 16, 64);
        lsum += __shfl_xor(lsum, 32, 64);
        if (lane == 0) atomicAdd(loss_s, lsum);
    }
}

// ---------------- exact fp32 re-argmin for tie-flagged pixels --------------
__global__ __launch_bounds__(256) void k_cleanup(const float* __restrict__ z,
        const float* __restrict__ emb, const float* __restrict__ ce2,
        const unsigned int* __restrict__ fbits,
        int* __restrict__ idx_i, float* __restrict__ idx_f, int* __restrict__ hist) {
    __shared__ float zs[1024];
    __shared__ float rv[4];
    __shared__ int ri[4];
    int t = threadIdx.x;
    const float* er = emb + (size_t)t * EDIM;
    for (int px = blockIdx.x; px < NPIX; px += gridDim.x) {
        if (!(fbits[px >> 5] & (1u << (px & 31)))) continue;   // uniform per block
        int b = px >> 10, p = px & 1023;
        const float* zb = z + (((size_t)b) << 20) + p;
        #pragma unroll
        for (int r = 0; r < 4; r++) {
            int c = t + 256 * r;
            zs[c] = zb[((size_t)c) << 10];
        }
        __syncthreads();
        float d0 = 0.f, d1 = 0.f, d2 = 0.f, d3 = 0.f;
        #pragma unroll 4
        for (int c = 0; c < EDIM; c += 16) {
            float4 e0 = *(const float4*)(er + c);
            float4 e1 = *(const float4*)(er + c + 4);
            float4 e2 = *(const float4*)(er + c + 8);
            float4 e3 = *(const float4*)(er + c + 12);
            d0 += e0.x * zs[c]      + e0.y * zs[c + 1]  + e0.z * zs[c + 2]  + e0.w * zs[c + 3];
            d1 += e1.x * zs[c + 4]  + e1.y * zs[c + 5]  + e1.z * zs[c + 6]  + e1.w * zs[c + 7];
            d2 += e2.x * zs[c + 8]  + e2.y * zs[c + 9]  + e2.z * zs[c + 10] + e2.w * zs[c + 11];
            d3 += e3.x * zs[c + 12] + e3.y * zs[c + 13] + e3.z * zs[c + 14] + e3.w * zs[c + 15];
        }
        float sv = ce2[t] - ((d0 + d1) + (d2 + d3));
        int bi = t;
        #pragma unroll
        for (int msk = 1; msk < 64; msk <<= 1) {
            float ov = __shfl_xor(sv, msk, 64);
            int oi = __shfl_xor(bi, msk, 64);
            if (ov < sv || (ov == sv && oi < bi)) { sv = ov; bi = oi; }
        }
        if ((t & 63) == 0) { rv[t >> 6] = sv; ri[t >> 6] = bi; }
        __syncthreads();
        if (t == 0) {
            float v = rv[0]; int ix = ri[0];
            for (int ww = 1; ww < 4; ww++)
                if (rv[ww] < v || (rv[ww] == v && ri[ww] < ix)) { v = rv[ww]; ix = ri[ww]; }
            int old = idx_i[px];
            if (ix != old) {
                idx_i[px] = ix; idx_f[px] = (float)ix;
                atomicAdd(&hist[ix], 1); atomicSub(&hist[old], 1);
            }
        }
        __syncthreads();
    }
}

// ---------------- round-1 fp32 argmin (fallback only) ----------------------
__global__ __launch_bounds__(64) void k_norms(const float* __restrict__ emb,
                                              float* __restrict__ ce2) {
    int j = blockIdx.x;
    int lane = threadIdx.x;
    const float* row = emb + (size_t)j * EDIM;
    float s = 0.f;
    #pragma unroll
    for (int i = 0; i < EDIM / 64; i++) {
        float v = row[lane + 64 * i];
        s += v * v;
    }
    #pragma unroll
    for (int m = 32; m; m >>= 1) s += __shfl_down(s, m, 64);
    if (lane == 0) ce2[j] = 0.5f * s;
}

__global__ __launch_bounds__(256) void k_argmin(const float* __restrict__ z,
                                                const float* __restrict__ emb,
                                                const float* __restrict__ ce2,
                                                int* __restrict__ idx_i,
                                                float* __restrict__ idx_f,
                                                int* __restrict__ hist,
                                                float* __restrict__ loss_acc) {
    __shared__ float zt[32 * 64];
    __shared__ float et[256 * 34];
    __shared__ float znorm_s[64];
    int t = threadIdx.x;
    int n0 = blockIdx.x * 64;
    int b = n0 >> 10;
    int p0 = n0 & 1023;
    const float* zb = z + (size_t)b * EDIM * HW;
    int tc = t & 31, tp = t >> 5;
    float acc[8][8] = {};
    float znorm = 0.f;
    for (int kk = 0; kk < EDIM; kk += 32) {
        #pragma unroll
        for (int i = 0; i < 16; i++) {
            int q = t + 256 * i;
            int code = q >> 4, k2 = q & 15;
            float2 v = *(const float2*)(emb + (size_t)code * EDIM + kk + k2 * 2);
            *(float2*)(et + code * 34 + k2 * 2) = v;
        }
        #pragma unroll
        for (int i = 0; i < 4; i++) {
            int q = t + 256 * i;
            int k = q >> 5, p2 = q & 31;
            float2 v = *(const float2*)(zb + (size_t)(kk + k) * HW + p0 + p2 * 2);
            *(float2*)(zt + k * 64 + p2 * 2) = v;
        }
        __syncthreads();
        if (t < 64) {
            #pragma unroll
            for (int k = 0; k < 32; k++) { float zz = zt[k * 64 + t]; znorm += zz * zz; }
        }
        #pragma unroll 4
        for (int k2 = 0; k2 < 16; k2++) {
            float2 ev[8], za[4], zb2[4];
            #pragma unroll
            for (int u = 0; u < 8; u++)
                ev[u] = *(float2*)(et + (tc + 32 * u) * 34 + k2 * 2);
            #pragma unroll
            for (int j = 0; j < 4; j++)
                za[j] = *(float2*)(zt + (2 * k2) * 64 + tp * 8 + 2 * j);
            #pragma unroll
            for (int j = 0; j < 4; j++)
                zb2[j] = *(float2*)(zt + (2 * k2 + 1) * 64 + tp * 8 + 2 * j);
            #pragma unroll
            for (int p = 0; p < 8; p++) {
                float z0 = (p & 1) ? za[p >> 1].y : za[p >> 1].x;
                float z1 = (p & 1) ? zb2[p >> 1].y : zb2[p >> 1].x;
                #pragma unroll
                for (int u = 0; u < 8; u++)
                    acc[p][u] += z0 * ev[u].x + z1 * ev[u].y;
            }
        }
        __syncthreads();
    }
    if (t < 64) znorm_s[t] = znorm;
    float minv[8];
    int mini[8];
    #pragma unroll
    for (int p = 0; p < 8; p++) { minv[p] = 3.4e38f; mini[p] = 0; }
    #pragma unroll
    for (int u = 0; u < 8; u++) {
        int code = tc + 32 * u;
        float cc2 = ce2[code];
        #pragma unroll
        for (int p = 0; p < 8; p++) {
            float s = cc2 - acc[p][u];
            if (s < minv[p] || (s == minv[p] && code < mini[p])) { minv[p] = s; mini[p] = code; }
        }
    }
    #pragma unroll
    for (int m = 1; m < 32; m <<= 1) {
        #pragma unroll
        for (int p = 0; p < 8; p++) {
            float ov = __shfl_xor(minv[p], m, 64);
            int oi = __shfl_xor(mini[p], m, 64);
            if (ov < minv[p] || (ov == minv[p] && oi < mini[p])) { minv[p] = ov; mini[p] = oi; }
        }
    }
    __syncthreads();
    if (tc == 0) {
        float dsum = 0.f;
        #pragma unroll
        for (int p = 0; p < 8; p++) {
            int lp = tp * 8 + p;
            int n = n0 + lp;
            idx_i[n] = mini[p];
            idx_f[n] = (float)mini[p];
            dsum += znorm_s[lp] + 2.f * minv[p];
            atomicAdd(&hist[mini[p]], 1);
        }
        atomicAdd(loss_acc, dsum);
    }
}

// ------ out[b][o][p] = T[o][idx[b][p]] + bias[o], + fused finalize --------
__global__ __launch_bounds__(256) void k_scatter_f(const float* __restrict__ T,
                                                   const float* __restrict__ bias,
                                                   const int* __restrict__ idx,
                                                   const int* __restrict__ hist,
                                                   const float* __restrict__ loss_s,
                                                   const float* __restrict__ zsq,
                                                   float* __restrict__ out) {
    __shared__ float Ts[16 * 256];
    __shared__ float bs[16];
    __shared__ float red[4];
    int t = threadIdx.x;
    int o0 = blockIdx.x * 16;
    int b = blockIdx.y;
    #pragma unroll
    for (int r = 0; r < 16; r++)
        Ts[r * 256 + t] = T[(size_t)(o0 + r) * NE + t];
    if (t < 16) bs[t] = bias[o0 + t];
    __syncthreads();
    int4 i4 = *(const int4*)(idx + b * HW + t * 4);
    #pragma unroll
    for (int r = 0; r < 16; r++) {
        const float* Tr = Ts + r * 256;
        float bb = bs[r];
        float4 v;
        v.x = Tr[i4.x] + bb;
        v.y = Tr[i4.y] + bb;
        v.z = Tr[i4.z] + bb;
        v.w = Tr[i4.w] + bb;
        *(float4*)(out + ((size_t)(b * EDIM + o0 + r) * HW) + t * 4) = v;
    }
    if (blockIdx.x == 0 && blockIdx.y == 0) {
        float em = (float)hist[t] * (1.0f / 16384.0f);
        float v = em * logf(em + 1e-10f);
        #pragma unroll
        for (int m = 32; m; m >>= 1) v += __shfl_down(v, m, 64);
        if ((t & 63) == 0) red[t >> 6] = v;
        __syncthreads();
        if (t == 0) {
            float s = red[0] + red[1] + red[2] + red[3];
            out[OUT_ELEMS] = (zsq[0] + 2.f * loss_s[0]) * 1.25f / 16777216.f;
            out[OUT_ELEMS + 1] = expf(-s);
        }
    }
}

// ---------------- fallback scatter + finalize ------------------------------
__global__ __launch_bounds__(256) void k_scatter(const float* __restrict__ T,
                                                 const float* __restrict__ bias,
                                                 const int* __restrict__ idx,
                                                 float* __restrict__ out) {
    __shared__ float Ts[16 * 256];
    __shared__ float bs[16];
    int t = threadIdx.x;
    int o0 = blockIdx.x * 16;
    int b = blockIdx.y;
    #pragma unroll
    for (int r = 0; r < 16; r++)
        Ts[r * 256 + t] = T[(size_t)(o0 + r) * NE + t];
    if (t < 16) bs[t] = bias[o0 + t];
    __syncthreads();
    int4 i4 = *(const int4*)(idx + b * HW + t * 4);
    #pragma unroll
    for (int r = 0; r < 16; r++) {
        const float* Tr = Ts + r * 256;
        float bb = bs[r];
        float4 v;
        v.x = Tr[i4.x] + bb;
        v.y = Tr[i4.y] + bb;
        v.z = Tr[i4.z] + bb;
        v.w = Tr[i4.w] + bb;
        *(float4*)(out + ((size_t)(b * EDIM + o0 + r) * HW) + t * 4) = v;
    }
}

__global__ __launch_bounds__(256) void k_final_old(const int* __restrict__ hist,
                                                   const float* __restrict__ loss_acc,
                                                   float* __restrict__ out) {
    __shared__ float red[4];
    int t = threadIdx.x;
    float em = (float)hist[t] * (1.0f / 16384.0f);
    float v = em * logf(em + 1e-10f);
    #pragma unroll
    for (int m = 32; m; m >>= 1) v += __shfl_down(v, m, 64);
    if ((t & 63) == 0) red[t >> 6] = v;
    __syncthreads();
    if (t == 0) {
        float s = red[0] + red[1] + red[2] + red[3];
        out[OUT_ELEMS] = loss_acc[0] * 1.25f / 16777216.f;
        out[OUT_ELEMS + 1] = expf(-s);
    }
}

extern "C" void kernel_launch(void* const* d_in, const int* in_sizes, int n_in,
                              void* d_out, int out_size, void* d_ws, size_t ws_size,
                              hipStream_t stream) {
    (void)in_sizes; (void)n_in; (void)out_size;
    const float* z      = (const float*)d_in[0];
    const float* emb    = (const float*)d_in[1];
    const float* conv_w = (const float*)d_in[2];
    const float* conv_b = (const float*)d_in[3];
    float* out = (float*)d_out;

    if (ws_size >= WS_NEED) {
        // ---- fast path: 5 dispatches; k_dist = v8 (8-wave, 2 waves/SIMD) ----
        int*   hist     = (int*)((char*)d_ws + WS_HIST);
        float* loss_s   = (float*)((char*)d_ws + WS_LOSS);
        float* zsq      = (float*)((char*)d_ws + WS_ZSQ);
        unsigned int* fbits = (unsigned int*)((char*)d_ws + WS_FBITS);
        float* T        = (float*)((char*)d_ws + WS_T);
        float* ce2      = (float*)((char*)d_ws + WS_CE2);
        int*   idx_i    = (int*)((char*)d_ws + WS_IDX);
        unsigned short* eh = (unsigned short*)((char*)d_ws + WS_EH);
        unsigned short* el = (unsigned short*)((char*)d_ws + WS_EL);
        float* idx_f = out + OUT_ELEMS + 2;

        k_prep<<<NE, 64, 0, stream>>>(emb, eh, el, ce2, (float4*)d_ws);
        k_wT<<<dim3(4, 16, 4), 256, 0, stream>>>(conv_w, emb, T);
        k_dist<<<256, 512, 0, stream>>>(z, eh, el, ce2, idx_i, idx_f,
                                        hist, loss_s, zsq, fbits);
        k_cleanup<<<256, 256, 0, stream>>>(z, emb, ce2, fbits, idx_i, idx_f, hist);
        k_scatter_f<<<dim3(64, 16), 256, 0, stream>>>(T, conv_b, idx_i,
                                                      hist, loss_s, zsq, out);
    } else {
        // ---- fallback: round-1 fp32 path ----
        float* ce2      = (float*)((char*)d_ws + WO_CE2);
        int*   hist     = (int*)((char*)d_ws + WO_HIST);
        float* loss_acc = (float*)((char*)d_ws + WO_LOSS);
        int*   idx_i    = (int*)((char*)d_ws + WO_IDX);
        float* T        = (float*)((char*)d_ws + WO_T);
        float* idx_f = out + OUT_ELEMS + 2;

        hipMemsetAsync(d_ws, 0, WO_TOTAL, stream);
        k_norms<<<NE, 64, 0, stream>>>(emb, ce2);
        k_wT<<<dim3(4, 16, 4), 256, 0, stream>>>(conv_w, emb, T);
        k_argmin<<<256, 256, 0, stream>>>(z, emb, ce2, idx_i, idx_f, hist, loss_acc);
        k_scatter<<<dim3(64, 16), 256, 0, stream>>>(T, conv_b, idx_i, out);
        k_final_old<<<1, 256, 0, stream>>>(hist, loss_acc, out);
    }
}